// Round 7
// baseline (194.138 us; speedup 1.0000x reference)
//
#include <hip/hip_runtime.h>
#include <math.h>

// Problem constants (B=2, N=2048, C=256, H=8, D=32)
#define Bb 2
#define Nn 2048
#define Cc 256
#define Hh 8
#define Dd 32
#define INNER 256           // H*D
#define TQKV 768            // 3*INNER
#define NROWS 4096          // B*N
#define EPSf 1e-5f
#define SCALEf 0.17677669529663687f  // 1/sqrt(32)

typedef unsigned short u16;
typedef short s16x8 __attribute__((ext_vector_type(8)));
typedef float f32x4 __attribute__((ext_vector_type(4)));
#define MFMA16 __builtin_amdgcn_mfma_f32_16x16x32_bf16

// workspace layout (float offsets); total 6,651,904 floats = 26.6 MB
// mpart/lpart alias the normed region (normed dead after proj; aohi/aolo
// written only at combine, after merge has consumed mpart/lpart).
#define OFF_NORMED 0u          // [4096][256] f32   (dead after proj)
#define OFF_MPART  0u          // [2][16][2048] f32 (aliases normed; dead after merge)
#define OFF_LPART  65536u      // [2][16][2048] f32
#define OFF_AOHI   0u          // [4096][256] u16   (aliases normed)
#define OFF_AOLO   524288u     // [4096][256] u16
#define OFF_GATE   1048576u    // [4096][256] f32 (sigmoid applied)
#define OFF_MM     2097152u    // [16][2048] f32:  m_i + log(l_i)
#define OFF_QHI    2129920u    // [4096][768] bf16 (as u16)
#define OFF_QLO    3702784u    // [4096][768] bf16 (as u16)
#define OFF_WHI    5275648u    // [1280][256] u16: Wqkv(Q-scaled) | Wgate | Wf
#define OFF_WLO    5439488u    // [1280][256] u16
#define OFF_P1     5603328u    // [4096][256] f32  partial (ihalf=1); p0 = d_out

// bf16 helpers (RNE)
__device__ inline u16 f2bf(float f) {
  union { float f; unsigned u; } v; v.f = f;
  unsigned r = v.u + 0x7fffu + ((v.u >> 16) & 1u);
  return (u16)(r >> 16);
}
__device__ inline float bf2f(u16 h) {
  union { unsigned u; float f; } v; v.u = ((unsigned)h) << 16;
  return v.f;
}

// ---------------------------------------------------------------------------
// Kernel 1: LayerNorm (biased variance)
// ---------------------------------------------------------------------------
__global__ __launch_bounds__(256) void ln_kernel(
    const float* __restrict__ x, const float* __restrict__ gam,
    const float* __restrict__ bet, float* __restrict__ normed) {
  int row = blockIdx.x;
  int tid = threadIdx.x;
  size_t base = (size_t)row * Cc;
  float v = x[base + tid];
  float s1 = v, s2 = v * v;
  #pragma unroll
  for (int off = 32; off; off >>= 1) {
    s1 += __shfl_xor(s1, off);
    s2 += __shfl_xor(s2, off);
  }
  __shared__ float w1[4], w2[4];
  if ((tid & 63) == 0) { w1[tid >> 6] = s1; w2[tid >> 6] = s2; }
  __syncthreads();
  s1 = w1[0] + w1[1] + w1[2] + w1[3];
  s2 = w2[0] + w2[1] + w2[2] + w2[3];
  float mu = s1 * (1.0f / Cc);
  float var = s2 * (1.0f / Cc) - mu * mu;
  float rstd = rsqrtf(var + EPSf);
  normed[base + tid] = (v - mu) * rstd * gam[tid] + bet[tid];
}

// ---------------------------------------------------------------------------
// Kernel 1b: weight split-bf16 conversion.
// ---------------------------------------------------------------------------
__global__ __launch_bounds__(256) void wconv_kernel(
    const float* __restrict__ Wqkv, const float* __restrict__ Wgate,
    const float* __restrict__ Wf, u16* __restrict__ whi, u16* __restrict__ wlo) {
  int row = blockIdx.x;
  int col = threadIdx.x;
  float v;
  if (row < TQKV) {
    v = Wqkv[(size_t)row * Cc + col];
    if (row < INNER) v *= SCALEf;   // fold attention scale into Q weights
  } else if (row < TQKV + INNER) {
    v = Wgate[(size_t)(row - TQKV) * Cc + col];
  } else {
    v = Wf[(size_t)(row - TQKV - INNER) * Cc + col];
  }
  u16 h = f2bf(v);
  whi[(size_t)row * Cc + col] = h;
  wlo[(size_t)row * Cc + col] = f2bf(v - bf2f(h));
}

// ---------------------------------------------------------------------------
// Kernel 2: fused projections via split-bf16 MFMA.
// ---------------------------------------------------------------------------
__global__ __launch_bounds__(256) void proj_kernel(
    const float* __restrict__ x, const float* __restrict__ normed,
    const u16* __restrict__ whi, const u16* __restrict__ wlo,
    const float* __restrict__ bgate,
    u16* __restrict__ qhi, u16* __restrict__ qlo, float* __restrict__ gate) {
  int ro = blockIdx.y * 64;
  int co = blockIdx.x * 64;             // 0..1023 (combined W rows)
  bool isGate = (co >= TQKV);
  const float* __restrict__ A = isGate ? x : normed;
  int tid = threadIdx.x;
  int w = tid >> 6, l = tid & 63;
  int l15 = l & 15, g = l >> 4;
  int srow = tid >> 2, sc = tid & 3;
  __shared__ u16 a_hi[64][72], a_lo[64][72];
  __shared__ u16 b_hi[64][72], b_lo[64][72];
  f32x4 acc[4] = {};
  for (int k0 = 0; k0 < Cc; k0 += 64) {
    __syncthreads();
    // stage A tile: fp32 -> split bf16
    #pragma unroll
    for (int q4 = 0; q4 < 4; q4++) {
      float4 f = *reinterpret_cast<const float4*>(
          &A[(size_t)(ro + srow) * Cc + k0 + 16 * sc + 4 * q4]);
      ushort4 h, lo;
      h.x = f2bf(f.x); lo.x = f2bf(f.x - bf2f(h.x));
      h.y = f2bf(f.y); lo.y = f2bf(f.y - bf2f(h.y));
      h.z = f2bf(f.z); lo.z = f2bf(f.z - bf2f(h.z));
      h.w = f2bf(f.w); lo.w = f2bf(f.w - bf2f(h.w));
      *reinterpret_cast<ushort4*>(&a_hi[srow][16 * sc + 4 * q4]) = h;
      *reinterpret_cast<ushort4*>(&a_lo[srow][16 * sc + 4 * q4]) = lo;
    }
    // stage W tile (pre-split u16)
    {
      size_t wb = (size_t)(co + srow) * Cc + k0 + 16 * sc;
      const uint4* sh = reinterpret_cast<const uint4*>(&whi[wb]);
      const uint4* sl = reinterpret_cast<const uint4*>(&wlo[wb]);
      *reinterpret_cast<uint4*>(&b_hi[srow][16 * sc]) = sh[0];
      *reinterpret_cast<uint4*>(&b_hi[srow][16 * sc + 8]) = sh[1];
      *reinterpret_cast<uint4*>(&b_lo[srow][16 * sc]) = sl[0];
      *reinterpret_cast<uint4*>(&b_lo[srow][16 * sc + 8]) = sl[1];
    }
    __syncthreads();
    #pragma unroll
    for (int ks = 0; ks < 2; ks++) {
      s16x8 wb_hi = *reinterpret_cast<const s16x8*>(&b_hi[16 * w + l15][8 * g + 32 * ks]);
      s16x8 wb_lo = *reinterpret_cast<const s16x8*>(&b_lo[16 * w + l15][8 * g + 32 * ks]);
      #pragma unroll
      for (int mt = 0; mt < 4; mt++) {
        s16x8 aa_hi = *reinterpret_cast<const s16x8*>(&a_hi[16 * mt + l15][8 * g + 32 * ks]);
        s16x8 aa_lo = *reinterpret_cast<const s16x8*>(&a_lo[16 * mt + l15][8 * g + 32 * ks]);
        acc[mt] = MFMA16(aa_hi, wb_hi, acc[mt], 0, 0, 0);
        acc[mt] = MFMA16(aa_hi, wb_lo, acc[mt], 0, 0, 0);
        acc[mt] = MFMA16(aa_lo, wb_hi, acc[mt], 0, 0, 0);
      }
    }
  }
  // epilogue: row = ro+16mt+4g+r, col = co+16w+l15
  if (!isGate) {
    int o = co + 16 * w + l15;
    #pragma unroll
    for (int mt = 0; mt < 4; mt++) {
      #pragma unroll
      for (int r = 0; r < 4; r++) {
        int row = ro + 16 * mt + 4 * g + r;
        float v = acc[mt][r];
        u16 hb = f2bf(v);
        qhi[(size_t)row * TQKV + o] = hb;
        qlo[(size_t)row * TQKV + o] = f2bf(v - bf2f(hb));
      }
    }
  } else {
    int o = co - TQKV + 16 * w + l15;
    float bg = bgate[o];
    #pragma unroll
    for (int mt = 0; mt < 4; mt++) {
      #pragma unroll
      for (int r = 0; r < 4; r++) {
        int row = ro + 16 * mt + 4 * g + r;
        float z = acc[mt][r] + bg;
        gate[(size_t)row * INNER + o] = 1.0f / (1.0f + __expf(-z));
      }
    }
  }
}

// ---------------------------------------------------------------------------
// Kernel 3: softmax stats, split over j (blockIdx.z = half). Per
// (b,h, i-strip, jhalf): partial M = max_j s_ij, L = sum_j exp(s_ij - M)
// over that half's 1024 j. Merged by merge_kernel.
// ---------------------------------------------------------------------------
__global__ __launch_bounds__(256) void stats_kernel(
    const u16* __restrict__ qhi, const u16* __restrict__ qlo,
    float* __restrict__ mpart, float* __restrict__ lpart) {
  int bh = blockIdx.y;
  int b = bh >> 3, h = bh & 7;
  int i0 = blockIdx.x * 64;
  int jhalf = blockIdx.z;
  int jt0 = 16 * jhalf;
  int tid = threadIdx.x;
  int w = tid >> 6;
  int l = tid & 63;
  int l15 = l & 15, g = l >> 4;
  __shared__ u16 q_hi[64][40], q_lo[64][40];
  __shared__ u16 k_hi[64][40], k_lo[64][40];
  __shared__ float red_m[4][64], red_l[4][64];

  int srow = tid >> 2, sc = tid & 3;
  {
    size_t gq = ((size_t)(b * Nn + i0 + srow)) * TQKV + h * Dd + 8 * sc;
    *reinterpret_cast<uint4*>(&q_hi[srow][8 * sc]) =
        *reinterpret_cast<const uint4*>(&qhi[gq]);
    *reinterpret_cast<uint4*>(&q_lo[srow][8 * sc]) =
        *reinterpret_cast<const uint4*>(&qlo[gq]);
  }
  // prefetch first K tile into registers
  size_t gk0 = ((size_t)(b * Nn + jt0 * 64 + srow)) * TQKV + INNER + h * Dd + 8 * sc;
  uint4 pk_h = *reinterpret_cast<const uint4*>(&qhi[gk0]);
  uint4 pk_l = *reinterpret_cast<const uint4*>(&qlo[gk0]);
  __syncthreads();
  s16x8 bq_hi[4], bq_lo[4];
  #pragma unroll
  for (int nt = 0; nt < 4; nt++) {
    bq_hi[nt] = *reinterpret_cast<const s16x8*>(&q_hi[l15 + 16 * nt][8 * g]);
    bq_lo[nt] = *reinterpret_cast<const s16x8*>(&q_lo[l15 + 16 * nt][8 * g]);
  }
  float m[4], lsum[4];
  #pragma unroll
  for (int nt = 0; nt < 4; nt++) { m[nt] = -INFINITY; lsum[nt] = 0.f; }

  for (int jt = jt0; jt < jt0 + 16; jt++) {
    __syncthreads();   // prev MFMA readers done with k_lds
    *reinterpret_cast<uint4*>(&k_hi[srow][8 * sc]) = pk_h;
    *reinterpret_cast<uint4*>(&k_lo[srow][8 * sc]) = pk_l;
    if (jt < jt0 + 15) {
      size_t gk = ((size_t)(b * Nn + (jt + 1) * 64 + srow)) * TQKV + INNER + h * Dd + 8 * sc;
      pk_h = *reinterpret_cast<const uint4*>(&qhi[gk]);
      pk_l = *reinterpret_cast<const uint4*>(&qlo[gk]);
    }
    __syncthreads();
    s16x8 ka_hi = *reinterpret_cast<const s16x8*>(&k_hi[l15 + 16 * w][8 * g]);
    s16x8 ka_lo = *reinterpret_cast<const s16x8*>(&k_lo[l15 + 16 * w][8 * g]);
    #pragma unroll
    for (int nt = 0; nt < 4; nt++) {
      f32x4 acc = {0.f, 0.f, 0.f, 0.f};
      acc = MFMA16(ka_hi, bq_hi[nt], acc, 0, 0, 0);
      acc = MFMA16(ka_hi, bq_lo[nt], acc, 0, 0, 0);
      acc = MFMA16(ka_lo, bq_hi[nt], acc, 0, 0, 0);
      float mt = fmaxf(fmaxf(acc[0], acc[1]), fmaxf(acc[2], acc[3]));
      float mn = fmaxf(m[nt], mt);
      float ls = __expf(acc[0] - mn) + __expf(acc[1] - mn) +
                 __expf(acc[2] - mn) + __expf(acc[3] - mn);
      lsum[nt] = lsum[nt] * __expf(m[nt] - mn) + ls;
      m[nt] = mn;
    }
  }
  #pragma unroll
  for (int off = 16; off <= 32; off <<= 1) {
    #pragma unroll
    for (int nt = 0; nt < 4; nt++) {
      float mo = __shfl_xor(m[nt], off);
      float lo = __shfl_xor(lsum[nt], off);
      float mn = fmaxf(m[nt], mo);
      lsum[nt] = lsum[nt] * __expf(m[nt] - mn) + lo * __expf(mo - mn);
      m[nt] = mn;
    }
  }
  if (g == 0) {
    #pragma unroll
    for (int nt = 0; nt < 4; nt++) {
      red_m[w][l15 + 16 * nt] = m[nt];
      red_l[w][l15 + 16 * nt] = lsum[nt];
    }
  }
  __syncthreads();
  if (tid < 64) {
    float M = fmaxf(fmaxf(red_m[0][tid], red_m[1][tid]),
                    fmaxf(red_m[2][tid], red_m[3][tid]));
    float L = red_l[0][tid] * __expf(red_m[0][tid] - M)
            + red_l[1][tid] * __expf(red_m[1][tid] - M)
            + red_l[2][tid] * __expf(red_m[2][tid] - M)
            + red_l[3][tid] * __expf(red_m[3][tid] - M);
    size_t o = ((size_t)(jhalf * 16 + bh)) * Nn + i0 + tid;
    mpart[o] = M;
    lpart[o] = L;
  }
}

// ---------------------------------------------------------------------------
// Kernel 3b: merge the two j-half stats: mm = M + log(sum of rescaled L).
// ---------------------------------------------------------------------------
__global__ __launch_bounds__(256) void merge_kernel(
    const float* __restrict__ mpart, const float* __restrict__ lpart,
    float* __restrict__ mmrow) {
  size_t idx = (size_t)blockIdx.x * 256 + threadIdx.x;   // 0..32767
  float m0 = mpart[idx], m1 = mpart[idx + 32768];
  float l0 = lpart[idx], l1 = lpart[idx + 32768];
  float M = fmaxf(m0, m1);
  mmrow[idx] = M + __logf(l0 * __expf(m0 - M) + l1 * __expf(m1 - M));
}

// ---------------------------------------------------------------------------
// Kernel 4: partial out[j,d] = sum_{i in half} exp(s_ij - mm_i) * v[i,d].
// Split over i (blockIdx.z). f32 partials (no gate); combined by
// combine_kernel. vt swizzle: pitch 72 + col = srow ^ 16*((d>>3)&3) ->
// the four d-groups of the scatter hit disjoint 8-bank sets (2 lanes/bank).
// ---------------------------------------------------------------------------
__global__ __launch_bounds__(256) void attnout_kernel(
    const u16* __restrict__ qhi, const u16* __restrict__ qlo,
    const float* __restrict__ mmrow,
    float* __restrict__ p0, float* __restrict__ p1) {
  int bh = blockIdx.y;
  int b = bh >> 3, h = bh & 7;
  int j0 = blockIdx.x * 64;
  int itbase = 16 * blockIdx.z;
  int tid = threadIdx.x;
  int w = tid >> 6;
  int l = tid & 63;
  int l15 = l & 15, g = l >> 4;
  __shared__ u16 k_hi[64][40], k_lo[64][40];
  __shared__ u16 q_hi[64][40], q_lo[64][40];
  __shared__ u16 vt_hi[32][72], vt_lo[32][72];
  __shared__ u16 p_hi[64][74], p_lo[64][74];
  __shared__ float mm_lds[64];

  int srow = tid >> 2, sc = tid & 3;
  {
    size_t gk = ((size_t)(b * Nn + j0 + srow)) * TQKV + INNER + h * Dd + 8 * sc;
    *reinterpret_cast<uint4*>(&k_hi[srow][8 * sc]) =
        *reinterpret_cast<const uint4*>(&qhi[gk]);
    *reinterpret_cast<uint4*>(&k_lo[srow][8 * sc]) =
        *reinterpret_cast<const uint4*>(&qlo[gk]);
  }
  // prefetch first tile (Q, V, mm) into registers
  size_t gq0 = ((size_t)(b * Nn + itbase * 64 + srow)) * TQKV + h * Dd + 8 * sc;
  uint4 pq_h = *reinterpret_cast<const uint4*>(&qhi[gq0]);
  uint4 pq_l = *reinterpret_cast<const uint4*>(&qlo[gq0]);
  uint4 pv_h = *reinterpret_cast<const uint4*>(&qhi[gq0 + 2 * INNER]);
  uint4 pv_l = *reinterpret_cast<const uint4*>(&qlo[gq0 + 2 * INNER]);
  float pmm = 0.f;
  if (tid < 64) pmm = mmrow[(size_t)bh * Nn + itbase * 64 + tid];
  __syncthreads();
  s16x8 kb_hi = *reinterpret_cast<const s16x8*>(&k_hi[l15 + 16 * w][8 * g]);
  s16x8 kb_lo = *reinterpret_cast<const s16x8*>(&k_lo[l15 + 16 * w][8 * g]);

  f32x4 accd0 = {0.f, 0.f, 0.f, 0.f};
  f32x4 accd1 = {0.f, 0.f, 0.f, 0.f};
  int swz0 = 16 * (l15 >> 3);        // vt read swizzle, row l15
  int swz1 = swz0 ^ 32;              // row l15+16

  for (int it = itbase; it < itbase + 16; it++) {
    __syncthreads();   // prev iter's LDS readers complete
    // write prefetched tile to LDS
    *reinterpret_cast<uint4*>(&q_hi[srow][8 * sc]) = pq_h;
    *reinterpret_cast<uint4*>(&q_lo[srow][8 * sc]) = pq_l;
    {
      const u16* vhp = reinterpret_cast<const u16*>(&pv_h);
      const u16* vlp = reinterpret_cast<const u16*>(&pv_l);
      #pragma unroll
      for (int e = 0; e < 8; e++) {
        int d = 8 * sc + e;
        int col = srow ^ (16 * ((d >> 3) & 3));
        vt_hi[d][col] = vhp[e];
        vt_lo[d][col] = vlp[e];
      }
    }
    if (tid < 64) mm_lds[tid] = pmm;
    // issue next-tile loads; they land during this tile's MFMA/exp work
    if (it < itbase + 15) {
      size_t gq = ((size_t)(b * Nn + (it + 1) * 64 + srow)) * TQKV + h * Dd + 8 * sc;
      pq_h = *reinterpret_cast<const uint4*>(&qhi[gq]);
      pq_l = *reinterpret_cast<const uint4*>(&qlo[gq]);
      pv_h = *reinterpret_cast<const uint4*>(&qhi[gq + 2 * INNER]);
      pv_l = *reinterpret_cast<const uint4*>(&qlo[gq + 2 * INNER]);
      if (tid < 64) pmm = mmrow[(size_t)bh * Nn + (it + 1) * 64 + tid];
    }
    __syncthreads();
    // QK^T + exp + split + store P[j][i]
    #pragma unroll
    for (int mt = 0; mt < 4; mt++) {
      s16x8 qa_hi = *reinterpret_cast<const s16x8*>(&q_hi[l15 + 16 * mt][8 * g]);
      s16x8 qa_lo = *reinterpret_cast<const s16x8*>(&q_lo[l15 + 16 * mt][8 * g]);
      f32x4 s = {0.f, 0.f, 0.f, 0.f};
      s = MFMA16(qa_hi, kb_hi, s, 0, 0, 0);
      s = MFMA16(qa_hi, kb_lo, s, 0, 0, 0);
      s = MFMA16(qa_lo, kb_hi, s, 0, 0, 0);
      int ib = 16 * mt + 4 * g;
      u16 ph[4], pl[4];
      #pragma unroll
      for (int r = 0; r < 4; r++) {
        float p = __expf(s[r] - mm_lds[ib + r]);
        u16 hb = f2bf(p);
        ph[r] = hb;
        pl[r] = f2bf(p - bf2f(hb));
      }
      ushort4 t1 = make_ushort4(ph[0], ph[1], ph[2], ph[3]);
      *reinterpret_cast<ushort4*>(&p_hi[l15 + 16 * w][ib]) = t1;
      ushort4 t2 = make_ushort4(pl[0], pl[1], pl[2], pl[3]);
      *reinterpret_cast<ushort4*>(&p_lo[l15 + 16 * w][ib]) = t2;
    }
    __syncthreads();
    // PV: D[m=j][n=d] += sum_i P^T[j,i] V[i,d]
    #pragma unroll
    for (int ks = 0; ks < 2; ks++) {
      s16x8 pa_hi = *reinterpret_cast<const s16x8*>(&p_hi[l15 + 16 * w][8 * g + 32 * ks]);
      s16x8 pa_lo = *reinterpret_cast<const s16x8*>(&p_lo[l15 + 16 * w][8 * g + 32 * ks]);
      int cb = 8 * g + 32 * ks;
      {
        s16x8 vb_hi = *reinterpret_cast<const s16x8*>(&vt_hi[l15][cb ^ swz0]);
        s16x8 vb_lo = *reinterpret_cast<const s16x8*>(&vt_lo[l15][cb ^ swz0]);
        accd0 = MFMA16(pa_hi, vb_hi, accd0, 0, 0, 0);
        accd0 = MFMA16(pa_hi, vb_lo, accd0, 0, 0, 0);
        accd0 = MFMA16(pa_lo, vb_hi, accd0, 0, 0, 0);
      }
      {
        s16x8 vb_hi = *reinterpret_cast<const s16x8*>(&vt_hi[l15 + 16][cb ^ swz1]);
        s16x8 vb_lo = *reinterpret_cast<const s16x8*>(&vt_lo[l15 + 16][cb ^ swz1]);
        accd1 = MFMA16(pa_hi, vb_hi, accd1, 0, 0, 0);
        accd1 = MFMA16(pa_hi, vb_lo, accd1, 0, 0, 0);
        accd1 = MFMA16(pa_lo, vb_hi, accd1, 0, 0, 0);
      }
    }
  }
  float* part = (blockIdx.z == 0) ? p0 : p1;
  #pragma unroll
  for (int r = 0; r < 4; r++) {
    int j = j0 + 16 * w + 4 * g + r;
    size_t rowb = ((size_t)(b * Nn + j)) * INNER + h * Dd;
    part[rowb + l15] = accd0[r];
    part[rowb + l15 + 16] = accd1[r];
  }
}

// ---------------------------------------------------------------------------
// Kernel 4b: combine partials, apply gate, split to bf16 for final GEMM.
// ---------------------------------------------------------------------------
__global__ __launch_bounds__(256) void combine_kernel(
    const float* __restrict__ p0, const float* __restrict__ p1,
    const float* __restrict__ gate,
    u16* __restrict__ aohi, u16* __restrict__ aolo) {
  size_t idx = (size_t)blockIdx.x * 256 + threadIdx.x;
  float v = (p0[idx] + p1[idx]) * gate[idx];
  u16 h = f2bf(v);
  aohi[idx] = h;
  aolo[idx] = f2bf(v - bf2f(h));
}

// ---------------------------------------------------------------------------
// Kernel 5: y = x + ao @ W_final^T + b_final via split-bf16 MFMA.
// ---------------------------------------------------------------------------
__global__ __launch_bounds__(256) void final_kernel(
    const u16* __restrict__ aohi, const u16* __restrict__ aolo,
    const u16* __restrict__ wfhi, const u16* __restrict__ wflo,
    const float* __restrict__ bf, const float* __restrict__ x,
    float* __restrict__ out) {
  int ro = blockIdx.y * 64;
  int co = blockIdx.x * 64;   // 0..255
  int tid = threadIdx.x;
  int w = tid >> 6, l = tid & 63;
  int l15 = l & 15, g = l >> 4;
  int srow = tid >> 2, sc = tid & 3;
  __shared__ u16 a_hi[64][72], a_lo[64][72];
  __shared__ u16 b_hi[64][72], b_lo[64][72];
  f32x4 acc[4] = {};
  for (int k0 = 0; k0 < INNER; k0 += 64) {
    __syncthreads();
    {
      size_t ab = (size_t)(ro + srow) * INNER + k0 + 16 * sc;
      const uint4* sh = reinterpret_cast<const uint4*>(&aohi[ab]);
      const uint4* sl = reinterpret_cast<const uint4*>(&aolo[ab]);
      *reinterpret_cast<uint4*>(&a_hi[srow][16 * sc]) = sh[0];
      *reinterpret_cast<uint4*>(&a_hi[srow][16 * sc + 8]) = sh[1];
      *reinterpret_cast<uint4*>(&a_lo[srow][16 * sc]) = sl[0];
      *reinterpret_cast<uint4*>(&a_lo[srow][16 * sc + 8]) = sl[1];
      size_t wb = (size_t)(co + srow) * Cc + k0 + 16 * sc;
      const uint4* th = reinterpret_cast<const uint4*>(&wfhi[wb]);
      const uint4* tl = reinterpret_cast<const uint4*>(&wflo[wb]);
      *reinterpret_cast<uint4*>(&b_hi[srow][16 * sc]) = th[0];
      *reinterpret_cast<uint4*>(&b_hi[srow][16 * sc + 8]) = th[1];
      *reinterpret_cast<uint4*>(&b_lo[srow][16 * sc]) = tl[0];
      *reinterpret_cast<uint4*>(&b_lo[srow][16 * sc + 8]) = tl[1];
    }
    __syncthreads();
    #pragma unroll
    for (int ks = 0; ks < 2; ks++) {
      s16x8 wb_hi = *reinterpret_cast<const s16x8*>(&b_hi[16 * w + l15][8 * g + 32 * ks]);
      s16x8 wb_lo = *reinterpret_cast<const s16x8*>(&b_lo[16 * w + l15][8 * g + 32 * ks]);
      #pragma unroll
      for (int mt = 0; mt < 4; mt++) {
        s16x8 aa_hi = *reinterpret_cast<const s16x8*>(&a_hi[16 * mt + l15][8 * g + 32 * ks]);
        s16x8 aa_lo = *reinterpret_cast<const s16x8*>(&a_lo[16 * mt + l15][8 * g + 32 * ks]);
        acc[mt] = MFMA16(aa_hi, wb_hi, acc[mt], 0, 0, 0);
        acc[mt] = MFMA16(aa_hi, wb_lo, acc[mt], 0, 0, 0);
        acc[mt] = MFMA16(aa_lo, wb_hi, acc[mt], 0, 0, 0);
      }
    }
  }
  int o = co + 16 * w + l15;
  float bfo = bf[o];
  #pragma unroll
  for (int mt = 0; mt < 4; mt++) {
    #pragma unroll
    for (int r = 0; r < 4; r++) {
      int row = ro + 16 * mt + 4 * g + r;
      out[(size_t)row * Cc + o] = x[(size_t)row * Cc + o] + acc[mt][r] + bfo;
    }
  }
}

// ---------------------------------------------------------------------------
extern "C" void kernel_launch(void* const* d_in, const int* in_sizes, int n_in,
                              void* d_out, int out_size, void* d_ws, size_t ws_size,
                              hipStream_t stream) {
  (void)in_sizes; (void)n_in; (void)out_size; (void)ws_size;
  const float* x     = (const float*)d_in[0];
  const float* gam   = (const float*)d_in[1];
  const float* bet   = (const float*)d_in[2];
  const float* Wqkv  = (const float*)d_in[3];
  const float* Wgate = (const float*)d_in[4];
  const float* bgate = (const float*)d_in[5];
  const float* Wf    = (const float*)d_in[6];
  const float* bf    = (const float*)d_in[7];
  float* out = (float*)d_out;
  float* ws  = (float*)d_ws;

  float* normed = ws + OFF_NORMED;
  float* gatep  = ws + OFF_GATE;
  float* mm     = ws + OFF_MM;
  float* mpart  = ws + OFF_MPART;          // aliases normed (dead after proj)
  float* lpart  = ws + OFF_LPART;
  float* part1  = ws + OFF_P1;
  u16*   qhi    = (u16*)(ws + OFF_QHI);
  u16*   qlo    = (u16*)(ws + OFF_QLO);
  u16*   whi    = (u16*)(ws + OFF_WHI);
  u16*   wlo    = (u16*)(ws + OFF_WLO);
  u16*   aohi   = (u16*)(ws + OFF_AOHI);   // aliases normed/mpart (dead then)
  u16*   aolo   = (u16*)(ws + OFF_AOLO);

  ln_kernel<<<NROWS, 256, 0, stream>>>(x, gam, bet, normed);
  wconv_kernel<<<1280, 256, 0, stream>>>(Wqkv, Wgate, Wf, whi, wlo);
  proj_kernel<<<dim3(16, 64), 256, 0, stream>>>(x, normed, whi, wlo, bgate,
                                                qhi, qlo, gatep);
  stats_kernel<<<dim3(32, 16, 2), 256, 0, stream>>>(qhi, qlo, mpart, lpart);
  merge_kernel<<<128, 256, 0, stream>>>(mpart, lpart, mm);
  attnout_kernel<<<dim3(32, 16, 2), 256, 0, stream>>>(qhi, qlo, mm, out, part1);
  combine_kernel<<<4096, 256, 0, stream>>>(out, part1, gatep, aohi, aolo);
  final_kernel<<<dim3(4, 64), 256, 0, stream>>>(aohi, aolo,
                                                whi + 1024 * Cc, wlo + 1024 * Cc,
                                                bf, x, out);
}

// Round 11
// 177.484 us; speedup vs baseline: 1.0938x; 1.0938x over previous
//
#include <hip/hip_runtime.h>
#include <math.h>

// Problem constants (B=2, N=2048, C=256, H=8, D=32)
#define Bb 2
#define Nn 2048
#define Cc 256
#define Hh 8
#define Dd 32
#define INNER 256           // H*D
#define TQKV 768            // 3*INNER
#define NROWS 4096          // B*N
#define EPSf 1e-5f
#define SCALEf 0.17677669529663687f  // 1/sqrt(32)

typedef unsigned short u16;
typedef short s16x8 __attribute__((ext_vector_type(8)));
typedef float f32x4 __attribute__((ext_vector_type(4)));
#define MFMA16 __builtin_amdgcn_mfma_f32_16x16x32_bf16

// workspace layout (float offsets); total 6,651,904 floats = 26.6 MB
// Region [0..1048576) is time-multiplexed (strict stream-order kills):
//   normed (ln->proj) ; mpart/lpart (stats->merge) ;
//   vtghi [0,524288) + vtglo [524288,1048576) (vtrans->attnout) ;
//   aohi  [0,524288) + aolo  [524288,1048576) (combine->final).
#define OFF_NORMED 0u          // [4096][256] f32
#define OFF_MPART  0u          // [2][16][2048] f32
#define OFF_LPART  65536u
#define OFF_VTGHI  0u          // [16][32][2048] u16  V^T hi  (524288 floats)
#define OFF_VTGLO  524288u     // [16][32][2048] u16  V^T lo
#define OFF_AOHI   0u          // [4096][256] u16 (after vtg dead)
#define OFF_AOLO   524288u     // [4096][256] u16
#define OFF_GATE   1048576u    // [4096][256] f32 (sigmoid applied)
#define OFF_MM     2097152u    // [16][2048] f32:  m_i + log(l_i)
#define OFF_QHI    2129920u    // [4096][768] bf16 (as u16)
#define OFF_QLO    3702784u    // [4096][768] bf16 (as u16)
#define OFF_WHI    5275648u    // [1280][256] u16: Wqkv(Q-scaled) | Wgate | Wf
#define OFF_WLO    5439488u    // [1280][256] u16
#define OFF_P1     5603328u    // [4096][256] f32  partial (ihalf=1); p0 = d_out

// bf16 helpers (RNE)
__device__ inline u16 f2bf(float f) {
  union { float f; unsigned u; } v; v.f = f;
  unsigned r = v.u + 0x7fffu + ((v.u >> 16) & 1u);
  return (u16)(r >> 16);
}
__device__ inline float bf2f(u16 h) {
  union { unsigned u; float f; } v; v.u = ((unsigned)h) << 16;
  return v.f;
}

// ---------------------------------------------------------------------------
// Kernel 1: LayerNorm (biased variance)
// ---------------------------------------------------------------------------
__global__ __launch_bounds__(256) void ln_kernel(
    const float* __restrict__ x, const float* __restrict__ gam,
    const float* __restrict__ bet, float* __restrict__ normed) {
  int row = blockIdx.x;
  int tid = threadIdx.x;
  size_t base = (size_t)row * Cc;
  float v = x[base + tid];
  float s1 = v, s2 = v * v;
  #pragma unroll
  for (int off = 32; off; off >>= 1) {
    s1 += __shfl_xor(s1, off);
    s2 += __shfl_xor(s2, off);
  }
  __shared__ float w1[4], w2[4];
  if ((tid & 63) == 0) { w1[tid >> 6] = s1; w2[tid >> 6] = s2; }
  __syncthreads();
  s1 = w1[0] + w1[1] + w1[2] + w1[3];
  s2 = w2[0] + w2[1] + w2[2] + w2[3];
  float mu = s1 * (1.0f / Cc);
  float var = s2 * (1.0f / Cc) - mu * mu;
  float rstd = rsqrtf(var + EPSf);
  normed[base + tid] = (v - mu) * rstd * gam[tid] + bet[tid];
}

// ---------------------------------------------------------------------------
// Kernel 1b: weight split-bf16 conversion.
// ---------------------------------------------------------------------------
__global__ __launch_bounds__(256) void wconv_kernel(
    const float* __restrict__ Wqkv, const float* __restrict__ Wgate,
    const float* __restrict__ Wf, u16* __restrict__ whi, u16* __restrict__ wlo) {
  int row = blockIdx.x;
  int col = threadIdx.x;
  float v;
  if (row < TQKV) {
    v = Wqkv[(size_t)row * Cc + col];
    if (row < INNER) v *= SCALEf;   // fold attention scale into Q weights
  } else if (row < TQKV + INNER) {
    v = Wgate[(size_t)(row - TQKV) * Cc + col];
  } else {
    v = Wf[(size_t)(row - TQKV - INNER) * Cc + col];
  }
  u16 h = f2bf(v);
  whi[(size_t)row * Cc + col] = h;
  wlo[(size_t)row * Cc + col] = f2bf(v - bf2f(h));
}

// ---------------------------------------------------------------------------
// Kernel 2: fused projections via split-bf16 MFMA.
// ---------------------------------------------------------------------------
__global__ __launch_bounds__(256) void proj_kernel(
    const float* __restrict__ x, const float* __restrict__ normed,
    const u16* __restrict__ whi, const u16* __restrict__ wlo,
    const float* __restrict__ bgate,
    u16* __restrict__ qhi, u16* __restrict__ qlo, float* __restrict__ gate) {
  int ro = blockIdx.y * 64;
  int co = blockIdx.x * 64;             // 0..1023 (combined W rows)
  bool isGate = (co >= TQKV);
  const float* __restrict__ A = isGate ? x : normed;
  int tid = threadIdx.x;
  int w = tid >> 6, l = tid & 63;
  int l15 = l & 15, g = l >> 4;
  int srow = tid >> 2, sc = tid & 3;
  __shared__ u16 a_hi[64][72], a_lo[64][72];
  __shared__ u16 b_hi[64][72], b_lo[64][72];
  f32x4 acc[4] = {};
  for (int k0 = 0; k0 < Cc; k0 += 64) {
    __syncthreads();
    #pragma unroll
    for (int q4 = 0; q4 < 4; q4++) {
      float4 f = *reinterpret_cast<const float4*>(
          &A[(size_t)(ro + srow) * Cc + k0 + 16 * sc + 4 * q4]);
      ushort4 h, lo;
      h.x = f2bf(f.x); lo.x = f2bf(f.x - bf2f(h.x));
      h.y = f2bf(f.y); lo.y = f2bf(f.y - bf2f(h.y));
      h.z = f2bf(f.z); lo.z = f2bf(f.z - bf2f(h.z));
      h.w = f2bf(f.w); lo.w = f2bf(f.w - bf2f(h.w));
      *reinterpret_cast<ushort4*>(&a_hi[srow][16 * sc + 4 * q4]) = h;
      *reinterpret_cast<ushort4*>(&a_lo[srow][16 * sc + 4 * q4]) = lo;
    }
    {
      size_t wb = (size_t)(co + srow) * Cc + k0 + 16 * sc;
      const uint4* sh = reinterpret_cast<const uint4*>(&whi[wb]);
      const uint4* sl = reinterpret_cast<const uint4*>(&wlo[wb]);
      *reinterpret_cast<uint4*>(&b_hi[srow][16 * sc]) = sh[0];
      *reinterpret_cast<uint4*>(&b_hi[srow][16 * sc + 8]) = sh[1];
      *reinterpret_cast<uint4*>(&b_lo[srow][16 * sc]) = sl[0];
      *reinterpret_cast<uint4*>(&b_lo[srow][16 * sc + 8]) = sl[1];
    }
    __syncthreads();
    #pragma unroll
    for (int ks = 0; ks < 2; ks++) {
      s16x8 wb_hi = *reinterpret_cast<const s16x8*>(&b_hi[16 * w + l15][8 * g + 32 * ks]);
      s16x8 wb_lo = *reinterpret_cast<const s16x8*>(&b_lo[16 * w + l15][8 * g + 32 * ks]);
      #pragma unroll
      for (int mt = 0; mt < 4; mt++) {
        s16x8 aa_hi = *reinterpret_cast<const s16x8*>(&a_hi[16 * mt + l15][8 * g + 32 * ks]);
        s16x8 aa_lo = *reinterpret_cast<const s16x8*>(&a_lo[16 * mt + l15][8 * g + 32 * ks]);
        acc[mt] = MFMA16(aa_hi, wb_hi, acc[mt], 0, 0, 0);
        acc[mt] = MFMA16(aa_hi, wb_lo, acc[mt], 0, 0, 0);
        acc[mt] = MFMA16(aa_lo, wb_hi, acc[mt], 0, 0, 0);
      }
    }
  }
  if (!isGate) {
    int o = co + 16 * w + l15;
    #pragma unroll
    for (int mt = 0; mt < 4; mt++) {
      #pragma unroll
      for (int r = 0; r < 4; r++) {
        int row = ro + 16 * mt + 4 * g + r;
        float v = acc[mt][r];
        u16 hb = f2bf(v);
        qhi[(size_t)row * TQKV + o] = hb;
        qlo[(size_t)row * TQKV + o] = f2bf(v - bf2f(hb));
      }
    }
  } else {
    int o = co - TQKV + 16 * w + l15;
    float bg = bgate[o];
    #pragma unroll
    for (int mt = 0; mt < 4; mt++) {
      #pragma unroll
      for (int r = 0; r < 4; r++) {
        int row = ro + 16 * mt + 4 * g + r;
        float z = acc[mt][r] + bg;
        gate[(size_t)row * INNER + o] = 1.0f / (1.0f + __expf(-z));
      }
    }
  }
}

// ---------------------------------------------------------------------------
// Kernel 3: softmax stats, split over j (blockIdx.z = half).
// ---------------------------------------------------------------------------
__global__ __launch_bounds__(256) void stats_kernel(
    const u16* __restrict__ qhi, const u16* __restrict__ qlo,
    float* __restrict__ mpart, float* __restrict__ lpart) {
  int bh = blockIdx.y;
  int b = bh >> 3, h = bh & 7;
  int i0 = blockIdx.x * 64;
  int jhalf = blockIdx.z;
  int jt0 = 16 * jhalf;
  int tid = threadIdx.x;
  int w = tid >> 6;
  int l = tid & 63;
  int l15 = l & 15, g = l >> 4;
  __shared__ u16 q_hi[64][40], q_lo[64][40];
  __shared__ u16 k_hi[64][40], k_lo[64][40];
  __shared__ float red_m[4][64], red_l[4][64];

  int srow = tid >> 2, sc = tid & 3;
  {
    size_t gq = ((size_t)(b * Nn + i0 + srow)) * TQKV + h * Dd + 8 * sc;
    *reinterpret_cast<uint4*>(&q_hi[srow][8 * sc]) =
        *reinterpret_cast<const uint4*>(&qhi[gq]);
    *reinterpret_cast<uint4*>(&q_lo[srow][8 * sc]) =
        *reinterpret_cast<const uint4*>(&qlo[gq]);
  }
  size_t gk0 = ((size_t)(b * Nn + jt0 * 64 + srow)) * TQKV + INNER + h * Dd + 8 * sc;
  uint4 pk_h = *reinterpret_cast<const uint4*>(&qhi[gk0]);
  uint4 pk_l = *reinterpret_cast<const uint4*>(&qlo[gk0]);
  __syncthreads();
  s16x8 bq_hi[4], bq_lo[4];
  #pragma unroll
  for (int nt = 0; nt < 4; nt++) {
    bq_hi[nt] = *reinterpret_cast<const s16x8*>(&q_hi[l15 + 16 * nt][8 * g]);
    bq_lo[nt] = *reinterpret_cast<const s16x8*>(&q_lo[l15 + 16 * nt][8 * g]);
  }
  float m[4], lsum[4];
  #pragma unroll
  for (int nt = 0; nt < 4; nt++) { m[nt] = -INFINITY; lsum[nt] = 0.f; }

  for (int jt = jt0; jt < jt0 + 16; jt++) {
    __syncthreads();
    *reinterpret_cast<uint4*>(&k_hi[srow][8 * sc]) = pk_h;
    *reinterpret_cast<uint4*>(&k_lo[srow][8 * sc]) = pk_l;
    if (jt < jt0 + 15) {
      size_t gk = ((size_t)(b * Nn + (jt + 1) * 64 + srow)) * TQKV + INNER + h * Dd + 8 * sc;
      pk_h = *reinterpret_cast<const uint4*>(&qhi[gk]);
      pk_l = *reinterpret_cast<const uint4*>(&qlo[gk]);
    }
    __syncthreads();
    s16x8 ka_hi = *reinterpret_cast<const s16x8*>(&k_hi[l15 + 16 * w][8 * g]);
    s16x8 ka_lo = *reinterpret_cast<const s16x8*>(&k_lo[l15 + 16 * w][8 * g]);
    #pragma unroll
    for (int nt = 0; nt < 4; nt++) {
      f32x4 acc = {0.f, 0.f, 0.f, 0.f};
      acc = MFMA16(ka_hi, bq_hi[nt], acc, 0, 0, 0);
      acc = MFMA16(ka_hi, bq_lo[nt], acc, 0, 0, 0);
      acc = MFMA16(ka_lo, bq_hi[nt], acc, 0, 0, 0);
      float mt = fmaxf(fmaxf(acc[0], acc[1]), fmaxf(acc[2], acc[3]));
      float mn = fmaxf(m[nt], mt);
      float ls = __expf(acc[0] - mn) + __expf(acc[1] - mn) +
                 __expf(acc[2] - mn) + __expf(acc[3] - mn);
      lsum[nt] = lsum[nt] * __expf(m[nt] - mn) + ls;
      m[nt] = mn;
    }
  }
  #pragma unroll
  for (int off = 16; off <= 32; off <<= 1) {
    #pragma unroll
    for (int nt = 0; nt < 4; nt++) {
      float mo = __shfl_xor(m[nt], off);
      float lo = __shfl_xor(lsum[nt], off);
      float mn = fmaxf(m[nt], mo);
      lsum[nt] = lsum[nt] * __expf(m[nt] - mn) + lo * __expf(mo - mn);
      m[nt] = mn;
    }
  }
  if (g == 0) {
    #pragma unroll
    for (int nt = 0; nt < 4; nt++) {
      red_m[w][l15 + 16 * nt] = m[nt];
      red_l[w][l15 + 16 * nt] = lsum[nt];
    }
  }
  __syncthreads();
  if (tid < 64) {
    float M = fmaxf(fmaxf(red_m[0][tid], red_m[1][tid]),
                    fmaxf(red_m[2][tid], red_m[3][tid]));
    float L = red_l[0][tid] * __expf(red_m[0][tid] - M)
            + red_l[1][tid] * __expf(red_m[1][tid] - M)
            + red_l[2][tid] * __expf(red_m[2][tid] - M)
            + red_l[3][tid] * __expf(red_m[3][tid] - M);
    size_t o = ((size_t)(jhalf * 16 + bh)) * Nn + i0 + tid;
    mpart[o] = M;
    lpart[o] = L;
  }
}

// ---------------------------------------------------------------------------
// Kernel 3b: merge the two j-half stats.
// ---------------------------------------------------------------------------
__global__ __launch_bounds__(256) void merge_kernel(
    const float* __restrict__ mpart, const float* __restrict__ lpart,
    float* __restrict__ mmrow) {
  size_t idx = (size_t)blockIdx.x * 256 + threadIdx.x;   // 0..32767
  float m0 = mpart[idx], m1 = mpart[idx + 32768];
  float l0 = lpart[idx], l1 = lpart[idx + 32768];
  float M = fmaxf(m0, m1);
  mmrow[idx] = M + __logf(l0 * __expf(m0 - M) + l1 * __expf(m1 - M));
}

// ---------------------------------------------------------------------------
// Kernel 3c: global V transpose -> vtg[bh][d][i] (hi/lo). LDS-free gather;
// each 64B V-row segment is read by the 32 d-threads of the same block (L1).
// Must run AFTER merge_kernel (vtg overwrites mpart/lpart region).
// ---------------------------------------------------------------------------
__global__ __launch_bounds__(256) void vtrans_kernel(
    const u16* __restrict__ qhi, const u16* __restrict__ qlo,
    u16* __restrict__ vtghi, u16* __restrict__ vtglo) {
  int bh = blockIdx.y;
  int b = bh >> 3, h = bh & 7;
  int ib = blockIdx.x;                 // 16 blocks x 128 i
  int t = threadIdx.x;
  int d = t >> 3;
  #pragma unroll
  for (int rep = 0; rep < 2; rep++) {
    int i0 = ib * 128 + 8 * (t & 7) + 64 * rep;
    union { u16 s[8]; uint4 v; } ah, al;
    #pragma unroll
    for (int e = 0; e < 8; e++) {
      size_t src = ((size_t)(b * Nn + i0 + e)) * TQKV + 2 * INNER + h * Dd + d;
      ah.s[e] = qhi[src];
      al.s[e] = qlo[src];
    }
    size_t dst = ((size_t)(bh * 32 + d)) * Nn + i0;
    *reinterpret_cast<uint4*>(&vtghi[dst]) = ah.v;
    *reinterpret_cast<uint4*>(&vtglo[dst]) = al.v;
  }
}

// ---------------------------------------------------------------------------
// Kernel 4: partial out[j,d] = sum_{i in half} exp(s_ij - mm_i) * v[i,d].
// V^T staged from pre-transposed global via clean b128 (no u16 scatter);
// K in per-wave registers (no LDS); P round-trip pitch 72 (16B-aligned).
// LDS ~37 KB -> 4 blocks/CU.
// ---------------------------------------------------------------------------
__global__ __launch_bounds__(256, 4) void attnout_kernel(
    const u16* __restrict__ qhi, const u16* __restrict__ qlo,
    const u16* __restrict__ vtghi, const u16* __restrict__ vtglo,
    const float* __restrict__ mmrow,
    float* __restrict__ p0, float* __restrict__ p1) {
  int bh = blockIdx.y;
  int b = bh >> 3, h = bh & 7;
  int j0 = blockIdx.x * 64;
  int itbase = 16 * blockIdx.z;
  int tid = threadIdx.x;
  int w = tid >> 6;
  int l = tid & 63;
  int l15 = l & 15, g = l >> 4;
  __shared__ u16 q_hi[64][40], q_lo[64][40];
  __shared__ u16 vt_hi[32][72], vt_lo[32][72];
  __shared__ u16 p_hi[64][72], p_lo[64][72];
  __shared__ float mm_lds[64];

  int srow = tid >> 2, sc = tid & 3;
  // K direct to registers: lane (l15,g) of wave w = row j0+16w+l15, k-octet 8g
  s16x8 kb_hi, kb_lo;
  {
    size_t gk = ((size_t)(b * Nn + j0 + 16 * w + l15)) * TQKV + INNER + h * Dd + 8 * g;
    kb_hi = *reinterpret_cast<const s16x8*>(&qhi[gk]);
    kb_lo = *reinterpret_cast<const s16x8*>(&qlo[gk]);
  }
  // prefetch tile 0 (Q rows, V^T rows, mm)
  size_t gq0 = ((size_t)(b * Nn + itbase * 64 + srow)) * TQKV + h * Dd + 8 * sc;
  uint4 pq_h = *reinterpret_cast<const uint4*>(&qhi[gq0]);
  uint4 pq_l = *reinterpret_cast<const uint4*>(&qlo[gq0]);
  int vrow = bh * 32 + (tid >> 3);
  int va = 8 * (tid & 7);
  size_t gv0 = (size_t)vrow * Nn + itbase * 64 + va;
  uint4 pv_h = *reinterpret_cast<const uint4*>(&vtghi[gv0]);
  uint4 pv_l = *reinterpret_cast<const uint4*>(&vtglo[gv0]);
  float pmm = 0.f;
  if (tid < 64) pmm = mmrow[(size_t)bh * Nn + itbase * 64 + tid];

  f32x4 accd0 = {0.f, 0.f, 0.f, 0.f};
  f32x4 accd1 = {0.f, 0.f, 0.f, 0.f};

  for (int it = itbase; it < itbase + 16; it++) {
    __syncthreads();   // prev iter's LDS readers complete
    *reinterpret_cast<uint4*>(&q_hi[srow][8 * sc]) = pq_h;
    *reinterpret_cast<uint4*>(&q_lo[srow][8 * sc]) = pq_l;
    *reinterpret_cast<uint4*>(&vt_hi[tid >> 3][va]) = pv_h;
    *reinterpret_cast<uint4*>(&vt_lo[tid >> 3][va]) = pv_l;
    if (tid < 64) mm_lds[tid] = pmm;
    if (it < itbase + 15) {   // T14: issue next-tile loads now
      size_t gq = ((size_t)(b * Nn + (it + 1) * 64 + srow)) * TQKV + h * Dd + 8 * sc;
      pq_h = *reinterpret_cast<const uint4*>(&qhi[gq]);
      pq_l = *reinterpret_cast<const uint4*>(&qlo[gq]);
      size_t gv = (size_t)vrow * Nn + (it + 1) * 64 + va;
      pv_h = *reinterpret_cast<const uint4*>(&vtghi[gv]);
      pv_l = *reinterpret_cast<const uint4*>(&vtglo[gv]);
      if (tid < 64) pmm = mmrow[(size_t)bh * Nn + (it + 1) * 64 + tid];
    }
    __syncthreads();
    // QK^T + exp + split + store P[j][i]  (wave-local P rows)
    #pragma unroll
    for (int mt = 0; mt < 4; mt++) {
      s16x8 qa_hi = *reinterpret_cast<const s16x8*>(&q_hi[l15 + 16 * mt][8 * g]);
      s16x8 qa_lo = *reinterpret_cast<const s16x8*>(&q_lo[l15 + 16 * mt][8 * g]);
      f32x4 s = {0.f, 0.f, 0.f, 0.f};
      s = MFMA16(qa_hi, kb_hi, s, 0, 0, 0);
      s = MFMA16(qa_hi, kb_lo, s, 0, 0, 0);
      s = MFMA16(qa_lo, kb_hi, s, 0, 0, 0);
      int ib = 16 * mt + 4 * g;
      u16 ph[4], pl[4];
      #pragma unroll
      for (int r = 0; r < 4; r++) {
        float p = __expf(s[r] - mm_lds[ib + r]);
        u16 hb = f2bf(p);
        ph[r] = hb;
        pl[r] = f2bf(p - bf2f(hb));
      }
      ushort4 t1 = make_ushort4(ph[0], ph[1], ph[2], ph[3]);
      *reinterpret_cast<ushort4*>(&p_hi[l15 + 16 * w][ib]) = t1;
      ushort4 t2 = make_ushort4(pl[0], pl[1], pl[2], pl[3]);
      *reinterpret_cast<ushort4*>(&p_lo[l15 + 16 * w][ib]) = t2;
    }
    // PV: D[m=j][n=d] += sum_i P^T[j,i] V[i,d]
    #pragma unroll
    for (int ks = 0; ks < 2; ks++) {
      s16x8 pa_hi = *reinterpret_cast<const s16x8*>(&p_hi[l15 + 16 * w][8 * g + 32 * ks]);
      s16x8 pa_lo = *reinterpret_cast<const s16x8*>(&p_lo[l15 + 16 * w][8 * g + 32 * ks]);
      int cb = 32 * ks + 8 * g;
      {
        s16x8 vb_hi = *reinterpret_cast<const s16x8*>(&vt_hi[l15][cb]);
        s16x8 vb_lo = *reinterpret_cast<const s16x8*>(&vt_lo[l15][cb]);
        accd0 = MFMA16(pa_hi, vb_hi, accd0, 0, 0, 0);
        accd0 = MFMA16(pa_hi, vb_lo, accd0, 0, 0, 0);
        accd0 = MFMA16(pa_lo, vb_hi, accd0, 0, 0, 0);
      }
      {
        s16x8 vb_hi = *reinterpret_cast<const s16x8*>(&vt_hi[l15 + 16][cb]);
        s16x8 vb_lo = *reinterpret_cast<const s16x8*>(&vt_lo[l15 + 16][cb]);
        accd1 = MFMA16(pa_hi, vb_hi, accd1, 0, 0, 0);
        accd1 = MFMA16(pa_hi, vb_lo, accd1, 0, 0, 0);
        accd1 = MFMA16(pa_lo, vb_hi, accd1, 0, 0, 0);
      }
    }
  }
  float* part = (blockIdx.z == 0) ? p0 : p1;
  #pragma unroll
  for (int r = 0; r < 4; r++) {
    int j = j0 + 16 * w + 4 * g + r;
    size_t rowb = ((size_t)(b * Nn + j)) * INNER + h * Dd;
    part[rowb + l15] = accd0[r];
    part[rowb + l15 + 16] = accd1[r];
  }
}

// ---------------------------------------------------------------------------
// Kernel 4b: combine partials, apply gate, split to bf16 for final GEMM.
// ---------------------------------------------------------------------------
__global__ __launch_bounds__(256) void combine_kernel(
    const float* __restrict__ p0, const float* __restrict__ p1,
    const float* __restrict__ gate,
    u16* __restrict__ aohi, u16* __restrict__ aolo) {
  size_t idx = (size_t)blockIdx.x * 256 + threadIdx.x;
  float v = (p0[idx] + p1[idx]) * gate[idx];
  u16 h = f2bf(v);
  aohi[idx] = h;
  aolo[idx] = f2bf(v - bf2f(h));
}

// ---------------------------------------------------------------------------
// Kernel 5: y = x + ao @ W_final^T + b_final via split-bf16 MFMA.
// ---------------------------------------------------------------------------
__global__ __launch_bounds__(256) void final_kernel(
    const u16* __restrict__ aohi, const u16* __restrict__ aolo,
    const u16* __restrict__ wfhi, const u16* __restrict__ wflo,
    const float* __restrict__ bf, const float* __restrict__ x,
    float* __restrict__ out) {
  int ro = blockIdx.y * 64;
  int co = blockIdx.x * 64;   // 0..255
  int tid = threadIdx.x;
  int w = tid >> 6, l = tid & 63;
  int l15 = l & 15, g = l >> 4;
  int srow = tid >> 2, sc = tid & 3;
  __shared__ u16 a_hi[64][72], a_lo[64][72];
  __shared__ u16 b_hi[64][72], b_lo[64][72];
  f32x4 acc[4] = {};
  for (int k0 = 0; k0 < INNER; k0 += 64) {
    __syncthreads();
    {
      size_t ab = (size_t)(ro + srow) * INNER + k0 + 16 * sc;
      const uint4* sh = reinterpret_cast<const uint4*>(&aohi[ab]);
      const uint4* sl = reinterpret_cast<const uint4*>(&aolo[ab]);
      *reinterpret_cast<uint4*>(&a_hi[srow][16 * sc]) = sh[0];
      *reinterpret_cast<uint4*>(&a_hi[srow][16 * sc + 8]) = sh[1];
      *reinterpret_cast<uint4*>(&a_lo[srow][16 * sc]) = sl[0];
      *reinterpret_cast<uint4*>(&a_lo[srow][16 * sc + 8]) = sl[1];
      size_t wb = (size_t)(co + srow) * Cc + k0 + 16 * sc;
      const uint4* th = reinterpret_cast<const uint4*>(&wfhi[wb]);
      const uint4* tl = reinterpret_cast<const uint4*>(&wflo[wb]);
      *reinterpret_cast<uint4*>(&b_hi[srow][16 * sc]) = th[0];
      *reinterpret_cast<uint4*>(&b_hi[srow][16 * sc + 8]) = th[1];
      *reinterpret_cast<uint4*>(&b_lo[srow][16 * sc]) = tl[0];
      *reinterpret_cast<uint4*>(&b_lo[srow][16 * sc + 8]) = tl[1];
    }
    __syncthreads();
    #pragma unroll
    for (int ks = 0; ks < 2; ks++) {
      s16x8 wb_hi = *reinterpret_cast<const s16x8*>(&b_hi[16 * w + l15][8 * g + 32 * ks]);
      s16x8 wb_lo = *reinterpret_cast<const s16x8*>(&b_lo[16 * w + l15][8 * g + 32 * ks]);
      #pragma unroll
      for (int mt = 0; mt < 4; mt++) {
        s16x8 aa_hi = *reinterpret_cast<const s16x8*>(&a_hi[16 * mt + l15][8 * g + 32 * ks]);
        s16x8 aa_lo = *reinterpret_cast<const s16x8*>(&a_lo[16 * mt + l15][8 * g + 32 * ks]);
        acc[mt] = MFMA16(aa_hi, wb_hi, acc[mt], 0, 0, 0);
        acc[mt] = MFMA16(aa_hi, wb_lo, acc[mt], 0, 0, 0);
        acc[mt] = MFMA16(aa_lo, wb_hi, acc[mt], 0, 0, 0);
      }
    }
  }
  int o = co + 16 * w + l15;
  float bfo = bf[o];
  #pragma unroll
  for (int mt = 0; mt < 4; mt++) {
    #pragma unroll
    for (int r = 0; r < 4; r++) {
      int row = ro + 16 * mt + 4 * g + r;
      out[(size_t)row * Cc + o] = x[(size_t)row * Cc + o] + acc[mt][r] + bfo;
    }
  }
}

// ---------------------------------------------------------------------------
extern "C" void kernel_launch(void* const* d_in, const int* in_sizes, int n_in,
                              void* d_out, int out_size, void* d_ws, size_t ws_size,
                              hipStream_t stream) {
  (void)in_sizes; (void)n_in; (void)out_size; (void)ws_size;
  const float* x     = (const float*)d_in[0];
  const float* gam   = (const float*)d_in[1];
  const float* bet   = (const float*)d_in[2];
  const float* Wqkv  = (const float*)d_in[3];
  const float* Wgate = (const float*)d_in[4];
  const float* bgate = (const float*)d_in[5];
  const float* Wf    = (const float*)d_in[6];
  const float* bf    = (const float*)d_in[7];
  float* out = (float*)d_out;
  float* ws  = (float*)d_ws;

  float* normed = ws + OFF_NORMED;
  float* gatep  = ws + OFF_GATE;
  float* mm     = ws + OFF_MM;
  float* mpart  = ws + OFF_MPART;
  float* lpart  = ws + OFF_LPART;
  float* part1  = ws + OFF_P1;
  u16*   qhi    = (u16*)(ws + OFF_QHI);
  u16*   qlo    = (u16*)(ws + OFF_QLO);
  u16*   whi    = (u16*)(ws + OFF_WHI);
  u16*   wlo    = (u16*)(ws + OFF_WLO);
  u16*   vtghi  = (u16*)(ws + OFF_VTGHI);
  u16*   vtglo  = (u16*)(ws + OFF_VTGLO);
  u16*   aohi   = (u16*)(ws + OFF_AOHI);
  u16*   aolo   = (u16*)(ws + OFF_AOLO);

  ln_kernel<<<NROWS, 256, 0, stream>>>(x, gam, bet, normed);
  wconv_kernel<<<1280, 256, 0, stream>>>(Wqkv, Wgate, Wf, whi, wlo);
  proj_kernel<<<dim3(16, 64), 256, 0, stream>>>(x, normed, whi, wlo, bgate,
                                                qhi, qlo, gatep);
  stats_kernel<<<dim3(32, 16, 2), 256, 0, stream>>>(qhi, qlo, mpart, lpart);
  merge_kernel<<<128, 256, 0, stream>>>(mpart, lpart, mm);
  vtrans_kernel<<<dim3(16, 16), 256, 0, stream>>>(qhi, qlo, vtghi, vtglo);
  attnout_kernel<<<dim3(32, 16, 2), 256, 0, stream>>>(qhi, qlo, vtghi, vtglo,
                                                      mm, out, part1);
  combine_kernel<<<4096, 256, 0, stream>>>(out, part1, gatep, aohi, aolo);
  final_kernel<<<dim3(4, 64), 256, 0, stream>>>(aohi, aolo,
                                                whi + 1024 * Cc, wlo + 1024 * Cc,
                                                bf, x, out);
}

// Round 13
// 149.420 us; speedup vs baseline: 1.2993x; 1.1878x over previous
//
#include <hip/hip_runtime.h>
#include <math.h>

// Problem constants (B=2, N=2048, C=256, H=8, D=32)
#define Bb 2
#define Nn 2048
#define Cc 256
#define Hh 8
#define Dd 32
#define INNER 256           // H*D
#define TQKV 768            // 3*INNER
#define NROWS 4096          // B*N
#define EPSf 1e-5f
#define SCALEf 0.17677669529663687f  // 1/sqrt(32)

typedef unsigned short u16;
typedef short s16x8 __attribute__((ext_vector_type(8)));
typedef float f32x4 __attribute__((ext_vector_type(4)));
#define MFMA16 __builtin_amdgcn_mfma_f32_16x16x32_bf16

// workspace layout (float offsets); total 6,651,904 floats = 26.6 MB
// Region [0..1048576) time-multiplexed (strict stream-order kills):
//   normed (ln->proj) ; mpart/lpart [0,262144) (stats->merge) ;
//   vtghi [0,524288) (vtrans->attnout) ;
//   aohi [0,524288) + aolo [524288,1048576) (combine->final).
// Freed qlo region [3702784,5275648) hosts bf16 partials p2/p3.
#define OFF_NORMED 0u          // [4096][256] f32
#define OFF_MPART  0u          // [4][16][2048] f32 (131072)
#define OFF_LPART  131072u     // [4][16][2048] f32
#define OFF_VTGHI  0u          // [16][32][2048] u16 (524288 floats)
#define OFF_AOHI   0u          // [4096][256] u16
#define OFF_AOLO   524288u     // [4096][256] u16
#define OFF_GATE   1048576u    // [4096][256] f32 (sigmoid applied)
#define OFF_MM     2097152u    // [16][2048] f32:  m_i + log(l_i)
#define OFF_QHI    2129920u    // [4096][768] bf16 (ends 3702784)
#define OFF_P2     3702784u    // [4096][256] bf16 partial (262144 floats)
#define OFF_P3     3964928u    // [4096][256] bf16 partial
#define OFF_WHI    5275648u    // [1280][256] u16: Wqkv(Q-scaled) | Wgate | Wf
#define OFF_WLO    5439488u    // [1280][256] u16
#define OFF_P0     5603328u    // [4096][256] bf16 partial
#define OFF_P1x    5865472u    // [4096][256] bf16 partial (ends 6127616)

// bf16 helpers (RNE)
__device__ inline u16 f2bf(float f) {
  union { float f; unsigned u; } v; v.f = f;
  unsigned r = v.u + 0x7fffu + ((v.u >> 16) & 1u);
  return (u16)(r >> 16);
}
__device__ inline float bf2f(u16 h) {
  union { unsigned u; float f; } v; v.u = ((unsigned)h) << 16;
  return v.f;
}

// ---------------------------------------------------------------------------
// Kernel 1: LayerNorm (biased variance)
// ---------------------------------------------------------------------------
__global__ __launch_bounds__(256) void ln_kernel(
    const float* __restrict__ x, const float* __restrict__ gam,
    const float* __restrict__ bet, float* __restrict__ normed) {
  int row = blockIdx.x;
  int tid = threadIdx.x;
  size_t base = (size_t)row * Cc;
  float v = x[base + tid];
  float s1 = v, s2 = v * v;
  #pragma unroll
  for (int off = 32; off; off >>= 1) {
    s1 += __shfl_xor(s1, off);
    s2 += __shfl_xor(s2, off);
  }
  __shared__ float w1[4], w2[4];
  if ((tid & 63) == 0) { w1[tid >> 6] = s1; w2[tid >> 6] = s2; }
  __syncthreads();
  s1 = w1[0] + w1[1] + w1[2] + w1[3];
  s2 = w2[0] + w2[1] + w2[2] + w2[3];
  float mu = s1 * (1.0f / Cc);
  float var = s2 * (1.0f / Cc) - mu * mu;
  float rstd = rsqrtf(var + EPSf);
  normed[base + tid] = (v - mu) * rstd * gam[tid] + bet[tid];
}

// ---------------------------------------------------------------------------
// Kernel 1b: weight split-bf16 conversion.
// ---------------------------------------------------------------------------
__global__ __launch_bounds__(256) void wconv_kernel(
    const float* __restrict__ Wqkv, const float* __restrict__ Wgate,
    const float* __restrict__ Wf, u16* __restrict__ whi, u16* __restrict__ wlo) {
  int row = blockIdx.x;
  int col = threadIdx.x;
  float v;
  if (row < TQKV) {
    v = Wqkv[(size_t)row * Cc + col];
    if (row < INNER) v *= SCALEf;   // fold attention scale into Q weights
  } else if (row < TQKV + INNER) {
    v = Wgate[(size_t)(row - TQKV) * Cc + col];
  } else {
    v = Wf[(size_t)(row - TQKV - INNER) * Cc + col];
  }
  u16 h = f2bf(v);
  whi[(size_t)row * Cc + col] = h;
  wlo[(size_t)row * Cc + col] = f2bf(v - bf2f(h));
}

// ---------------------------------------------------------------------------
// Kernel 2: fused projections via split-bf16 MFMA (3-term, fp32-grade).
// qkv outputs written as bf16 HI ONLY (attention path tolerates 2^-9).
// ---------------------------------------------------------------------------
__global__ __launch_bounds__(256) void proj_kernel(
    const float* __restrict__ x, const float* __restrict__ normed,
    const u16* __restrict__ whi, const u16* __restrict__ wlo,
    const float* __restrict__ bgate,
    u16* __restrict__ qhi, float* __restrict__ gate) {
  int ro = blockIdx.y * 64;
  int co = blockIdx.x * 64;             // 0..1023 (combined W rows)
  bool isGate = (co >= TQKV);
  const float* __restrict__ A = isGate ? x : normed;
  int tid = threadIdx.x;
  int w = tid >> 6, l = tid & 63;
  int l15 = l & 15, g = l >> 4;
  int srow = tid >> 2, sc = tid & 3;
  __shared__ u16 a_hi[64][72], a_lo[64][72];
  __shared__ u16 b_hi[64][72], b_lo[64][72];
  f32x4 acc[4] = {};
  for (int k0 = 0; k0 < Cc; k0 += 64) {
    __syncthreads();
    #pragma unroll
    for (int q4 = 0; q4 < 4; q4++) {
      float4 f = *reinterpret_cast<const float4*>(
          &A[(size_t)(ro + srow) * Cc + k0 + 16 * sc + 4 * q4]);
      ushort4 h, lo;
      h.x = f2bf(f.x); lo.x = f2bf(f.x - bf2f(h.x));
      h.y = f2bf(f.y); lo.y = f2bf(f.y - bf2f(h.y));
      h.z = f2bf(f.z); lo.z = f2bf(f.z - bf2f(h.z));
      h.w = f2bf(f.w); lo.w = f2bf(f.w - bf2f(h.w));
      *reinterpret_cast<ushort4*>(&a_hi[srow][16 * sc + 4 * q4]) = h;
      *reinterpret_cast<ushort4*>(&a_lo[srow][16 * sc + 4 * q4]) = lo;
    }
    {
      size_t wb = (size_t)(co + srow) * Cc + k0 + 16 * sc;
      const uint4* sh = reinterpret_cast<const uint4*>(&whi[wb]);
      const uint4* sl = reinterpret_cast<const uint4*>(&wlo[wb]);
      *reinterpret_cast<uint4*>(&b_hi[srow][16 * sc]) = sh[0];
      *reinterpret_cast<uint4*>(&b_hi[srow][16 * sc + 8]) = sh[1];
      *reinterpret_cast<uint4*>(&b_lo[srow][16 * sc]) = sl[0];
      *reinterpret_cast<uint4*>(&b_lo[srow][16 * sc + 8]) = sl[1];
    }
    __syncthreads();
    #pragma unroll
    for (int ks = 0; ks < 2; ks++) {
      s16x8 wb_hi = *reinterpret_cast<const s16x8*>(&b_hi[16 * w + l15][8 * g + 32 * ks]);
      s16x8 wb_lo = *reinterpret_cast<const s16x8*>(&b_lo[16 * w + l15][8 * g + 32 * ks]);
      #pragma unroll
      for (int mt = 0; mt < 4; mt++) {
        s16x8 aa_hi = *reinterpret_cast<const s16x8*>(&a_hi[16 * mt + l15][8 * g + 32 * ks]);
        s16x8 aa_lo = *reinterpret_cast<const s16x8*>(&a_lo[16 * mt + l15][8 * g + 32 * ks]);
        acc[mt] = MFMA16(aa_hi, wb_hi, acc[mt], 0, 0, 0);
        acc[mt] = MFMA16(aa_hi, wb_lo, acc[mt], 0, 0, 0);
        acc[mt] = MFMA16(aa_lo, wb_hi, acc[mt], 0, 0, 0);
      }
    }
  }
  if (!isGate) {
    int o = co + 16 * w + l15;
    #pragma unroll
    for (int mt = 0; mt < 4; mt++) {
      #pragma unroll
      for (int r = 0; r < 4; r++) {
        int row = ro + 16 * mt + 4 * g + r;
        qhi[(size_t)row * TQKV + o] = f2bf(acc[mt][r]);
      }
    }
  } else {
    int o = co - TQKV + 16 * w + l15;
    float bg = bgate[o];
    #pragma unroll
    for (int mt = 0; mt < 4; mt++) {
      #pragma unroll
      for (int r = 0; r < 4; r++) {
        int row = ro + 16 * mt + 4 * g + r;
        float z = acc[mt][r] + bg;
        gate[(size_t)row * INNER + o] = 1.0f / (1.0f + __expf(-z));
      }
    }
  }
}

// ---------------------------------------------------------------------------
// Kernel 3: softmax stats, hi-only MFMA, split over j quarters (blockIdx.z).
// ---------------------------------------------------------------------------
__global__ __launch_bounds__(256, 8) void stats_kernel(
    const u16* __restrict__ qhi,
    float* __restrict__ mpart, float* __restrict__ lpart) {
  int bh = blockIdx.y;
  int b = bh >> 3, h = bh & 7;
  int i0 = blockIdx.x * 64;
  int jq = blockIdx.z;
  int jt0 = 8 * jq;
  int tid = threadIdx.x;
  int w = tid >> 6;
  int l = tid & 63;
  int l15 = l & 15, g = l >> 4;
  __shared__ u16 q_hi[64][40];
  __shared__ u16 k_hi[64][40];
  __shared__ float red_m[4][64], red_l[4][64];

  int srow = tid >> 2, sc = tid & 3;
  {
    size_t gq = ((size_t)(b * Nn + i0 + srow)) * TQKV + h * Dd + 8 * sc;
    *reinterpret_cast<uint4*>(&q_hi[srow][8 * sc]) =
        *reinterpret_cast<const uint4*>(&qhi[gq]);
  }
  size_t gk0 = ((size_t)(b * Nn + jt0 * 64 + srow)) * TQKV + INNER + h * Dd + 8 * sc;
  uint4 pk_h = *reinterpret_cast<const uint4*>(&qhi[gk0]);
  __syncthreads();
  s16x8 bq_hi[4];
  #pragma unroll
  for (int nt = 0; nt < 4; nt++)
    bq_hi[nt] = *reinterpret_cast<const s16x8*>(&q_hi[l15 + 16 * nt][8 * g]);
  float m[4], lsum[4];
  #pragma unroll
  for (int nt = 0; nt < 4; nt++) { m[nt] = -INFINITY; lsum[nt] = 0.f; }

  for (int jt = jt0; jt < jt0 + 8; jt++) {
    __syncthreads();
    *reinterpret_cast<uint4*>(&k_hi[srow][8 * sc]) = pk_h;
    if (jt < jt0 + 7) {
      size_t gk = ((size_t)(b * Nn + (jt + 1) * 64 + srow)) * TQKV + INNER + h * Dd + 8 * sc;
      pk_h = *reinterpret_cast<const uint4*>(&qhi[gk]);
    }
    __syncthreads();
    s16x8 ka_hi = *reinterpret_cast<const s16x8*>(&k_hi[l15 + 16 * w][8 * g]);
    #pragma unroll
    for (int nt = 0; nt < 4; nt++) {
      f32x4 acc = {0.f, 0.f, 0.f, 0.f};
      acc = MFMA16(ka_hi, bq_hi[nt], acc, 0, 0, 0);
      float mt = fmaxf(fmaxf(acc[0], acc[1]), fmaxf(acc[2], acc[3]));
      float mn = fmaxf(m[nt], mt);
      float ls = __expf(acc[0] - mn) + __expf(acc[1] - mn) +
                 __expf(acc[2] - mn) + __expf(acc[3] - mn);
      lsum[nt] = lsum[nt] * __expf(m[nt] - mn) + ls;
      m[nt] = mn;
    }
  }
  #pragma unroll
  for (int off = 16; off <= 32; off <<= 1) {
    #pragma unroll
    for (int nt = 0; nt < 4; nt++) {
      float mo = __shfl_xor(m[nt], off);
      float lo = __shfl_xor(lsum[nt], off);
      float mn = fmaxf(m[nt], mo);
      lsum[nt] = lsum[nt] * __expf(m[nt] - mn) + lo * __expf(mo - mn);
      m[nt] = mn;
    }
  }
  if (g == 0) {
    #pragma unroll
    for (int nt = 0; nt < 4; nt++) {
      red_m[w][l15 + 16 * nt] = m[nt];
      red_l[w][l15 + 16 * nt] = lsum[nt];
    }
  }
  __syncthreads();
  if (tid < 64) {
    float M = fmaxf(fmaxf(red_m[0][tid], red_m[1][tid]),
                    fmaxf(red_m[2][tid], red_m[3][tid]));
    float L = red_l[0][tid] * __expf(red_m[0][tid] - M)
            + red_l[1][tid] * __expf(red_m[1][tid] - M)
            + red_l[2][tid] * __expf(red_m[2][tid] - M)
            + red_l[3][tid] * __expf(red_m[3][tid] - M);
    size_t o = ((size_t)(jq * 16 + bh)) * Nn + i0 + tid;
    mpart[o] = M;
    lpart[o] = L;
  }
}

// ---------------------------------------------------------------------------
// Kernel 3b: merge the four j-quarter stats.
// ---------------------------------------------------------------------------
__global__ __launch_bounds__(256) void merge_kernel(
    const float* __restrict__ mpart, const float* __restrict__ lpart,
    float* __restrict__ mmrow) {
  size_t idx = (size_t)blockIdx.x * 256 + threadIdx.x;   // 0..32767
  float m0 = mpart[idx], m1 = mpart[idx + 32768];
  float m2 = mpart[idx + 65536], m3 = mpart[idx + 98304];
  float l0 = lpart[idx], l1 = lpart[idx + 32768];
  float l2 = lpart[idx + 65536], l3 = lpart[idx + 98304];
  float M = fmaxf(fmaxf(m0, m1), fmaxf(m2, m3));
  float L = l0 * __expf(m0 - M) + l1 * __expf(m1 - M) +
            l2 * __expf(m2 - M) + l3 * __expf(m3 - M);
  mmrow[idx] = M + __logf(L);
}

// ---------------------------------------------------------------------------
// Kernel 3c: global V transpose -> vtg[bh][d][i] (hi only).
// Must run AFTER merge_kernel (vtg overwrites mpart/lpart region).
// ---------------------------------------------------------------------------
__global__ __launch_bounds__(256) void vtrans_kernel(
    const u16* __restrict__ qhi, u16* __restrict__ vtghi) {
  int bh = blockIdx.y;
  int b = bh >> 3, h = bh & 7;
  int ib = blockIdx.x;                 // 16 blocks x 128 i
  int t = threadIdx.x;
  int d = t >> 3;
  #pragma unroll
  for (int rep = 0; rep < 2; rep++) {
    int i0 = ib * 128 + 8 * (t & 7) + 64 * rep;
    union { u16 s[8]; uint4 v; } ah;
    #pragma unroll
    for (int e = 0; e < 8; e++) {
      size_t src = ((size_t)(b * Nn + i0 + e)) * TQKV + 2 * INNER + h * Dd + d;
      ah.s[e] = qhi[src];
    }
    size_t dst = ((size_t)(bh * 32 + d)) * Nn + i0;
    *reinterpret_cast<uint4*>(&vtghi[dst]) = ah.v;
  }
}

// ---------------------------------------------------------------------------
// Kernel 4: partial out[j,d] = sum_{i in quarter} exp(s_ij - mm_i)*v[i,d].
// Hi-only MFMA (8/iter). i split over 4 (blockIdx.z); bf16 partials.
// LDS ~19 KB -> 8 blocks/CU.
// ---------------------------------------------------------------------------
__global__ __launch_bounds__(256, 8) void attnout_kernel(
    const u16* __restrict__ qhi, const u16* __restrict__ vtghi,
    const float* __restrict__ mmrow,
    u16* __restrict__ p0, u16* __restrict__ p1,
    u16* __restrict__ p2, u16* __restrict__ p3) {
  int bh = blockIdx.y;
  int b = bh >> 3, h = bh & 7;
  int j0 = blockIdx.x * 64;
  int itbase = 8 * blockIdx.z;
  int tid = threadIdx.x;
  int w = tid >> 6;
  int l = tid & 63;
  int l15 = l & 15, g = l >> 4;
  __shared__ u16 q_hi[64][40];
  __shared__ u16 vt_hi[32][72];
  __shared__ u16 p_hi[64][72];
  __shared__ float mm_lds[64];

  int srow = tid >> 2, sc = tid & 3;
  // K direct to registers: lane (l15,g) of wave w = row j0+16w+l15, k-octet 8g
  s16x8 kb_hi;
  {
    size_t gk = ((size_t)(b * Nn + j0 + 16 * w + l15)) * TQKV + INNER + h * Dd + 8 * g;
    kb_hi = *reinterpret_cast<const s16x8*>(&qhi[gk]);
  }
  // prefetch tile 0 (Q rows, V^T rows, mm)
  size_t gq0 = ((size_t)(b * Nn + itbase * 64 + srow)) * TQKV + h * Dd + 8 * sc;
  uint4 pq_h = *reinterpret_cast<const uint4*>(&qhi[gq0]);
  int vrow = bh * 32 + (tid >> 3);
  int va = 8 * (tid & 7);
  size_t gv0 = (size_t)vrow * Nn + itbase * 64 + va;
  uint4 pv_h = *reinterpret_cast<const uint4*>(&vtghi[gv0]);
  float pmm = 0.f;
  if (tid < 64) pmm = mmrow[(size_t)bh * Nn + itbase * 64 + tid];

  f32x4 accd0 = {0.f, 0.f, 0.f, 0.f};
  f32x4 accd1 = {0.f, 0.f, 0.f, 0.f};

  for (int it = itbase; it < itbase + 8; it++) {
    __syncthreads();   // prev iter's LDS readers complete
    *reinterpret_cast<uint4*>(&q_hi[srow][8 * sc]) = pq_h;
    *reinterpret_cast<uint4*>(&vt_hi[tid >> 3][va]) = pv_h;
    if (tid < 64) mm_lds[tid] = pmm;
    if (it < itbase + 7) {   // T14: issue next-tile loads now
      size_t gq = ((size_t)(b * Nn + (it + 1) * 64 + srow)) * TQKV + h * Dd + 8 * sc;
      pq_h = *reinterpret_cast<const uint4*>(&qhi[gq]);
      size_t gv = (size_t)vrow * Nn + (it + 1) * 64 + va;
      pv_h = *reinterpret_cast<const uint4*>(&vtghi[gv]);
      if (tid < 64) pmm = mmrow[(size_t)bh * Nn + (it + 1) * 64 + tid];
    }
    __syncthreads();
    // QK^T + exp + store P[j][i]  (wave-local P rows)
    #pragma unroll
    for (int mt = 0; mt < 4; mt++) {
      s16x8 qa_hi = *reinterpret_cast<const s16x8*>(&q_hi[l15 + 16 * mt][8 * g]);
      f32x4 s = {0.f, 0.f, 0.f, 0.f};
      s = MFMA16(qa_hi, kb_hi, s, 0, 0, 0);
      int ib = 16 * mt + 4 * g;
      u16 ph[4];
      #pragma unroll
      for (int r = 0; r < 4; r++)
        ph[r] = f2bf(__expf(s[r] - mm_lds[ib + r]));
      *reinterpret_cast<ushort4*>(&p_hi[l15 + 16 * w][ib]) =
          make_ushort4(ph[0], ph[1], ph[2], ph[3]);
    }
    // PV: D[m=j][n=d] += sum_i P^T[j,i] V[i,d]
    #pragma unroll
    for (int ks = 0; ks < 2; ks++) {
      s16x8 pa_hi = *reinterpret_cast<const s16x8*>(&p_hi[l15 + 16 * w][8 * g + 32 * ks]);
      int cb = 32 * ks + 8 * g;
      s16x8 vb0 = *reinterpret_cast<const s16x8*>(&vt_hi[l15][cb]);
      accd0 = MFMA16(pa_hi, vb0, accd0, 0, 0, 0);
      s16x8 vb1 = *reinterpret_cast<const s16x8*>(&vt_hi[l15 + 16][cb]);
      accd1 = MFMA16(pa_hi, vb1, accd1, 0, 0, 0);
    }
  }
  int z = blockIdx.z;
  u16* part = (z == 0) ? p0 : (z == 1) ? p1 : (z == 2) ? p2 : p3;
  #pragma unroll
  for (int r = 0; r < 4; r++) {
    int j = j0 + 16 * w + 4 * g + r;
    size_t rowb = ((size_t)(b * Nn + j)) * INNER + h * Dd;
    part[rowb + l15] = f2bf(accd0[r]);
    part[rowb + l15 + 16] = f2bf(accd1[r]);
  }
}

// ---------------------------------------------------------------------------
// Kernel 4b: combine bf16 partials, apply gate, split to bf16 for final GEMM.
// ---------------------------------------------------------------------------
__global__ __launch_bounds__(256) void combine_kernel(
    const u16* __restrict__ p0, const u16* __restrict__ p1,
    const u16* __restrict__ p2, const u16* __restrict__ p3,
    const float* __restrict__ gate,
    u16* __restrict__ aohi, u16* __restrict__ aolo) {
  size_t idx = (size_t)blockIdx.x * 256 + threadIdx.x;
  float v = (bf2f(p0[idx]) + bf2f(p1[idx]) + bf2f(p2[idx]) + bf2f(p3[idx]))
            * gate[idx];
  u16 h = f2bf(v);
  aohi[idx] = h;
  aolo[idx] = f2bf(v - bf2f(h));
}

// ---------------------------------------------------------------------------
// Kernel 5: y = x + ao @ W_final^T + b_final via split-bf16 MFMA.
// ---------------------------------------------------------------------------
__global__ __launch_bounds__(256) void final_kernel(
    const u16* __restrict__ aohi, const u16* __restrict__ aolo,
    const u16* __restrict__ wfhi, const u16* __restrict__ wflo,
    const float* __restrict__ bf, const float* __restrict__ x,
    float* __restrict__ out) {
  int ro = blockIdx.y * 64;
  int co = blockIdx.x * 64;   // 0..255
  int tid = threadIdx.x;
  int w = tid >> 6, l = tid & 63;
  int l15 = l & 15, g = l >> 4;
  int srow = tid >> 2, sc = tid & 3;
  __shared__ u16 a_hi[64][72], a_lo[64][72];
  __shared__ u16 b_hi[64][72], b_lo[64][72];
  f32x4 acc[4] = {};
  for (int k0 = 0; k0 < INNER; k0 += 64) {
    __syncthreads();
    {
      size_t ab = (size_t)(ro + srow) * INNER + k0 + 16 * sc;
      const uint4* sh = reinterpret_cast<const uint4*>(&aohi[ab]);
      const uint4* sl = reinterpret_cast<const uint4*>(&aolo[ab]);
      *reinterpret_cast<uint4*>(&a_hi[srow][16 * sc]) = sh[0];
      *reinterpret_cast<uint4*>(&a_hi[srow][16 * sc + 8]) = sh[1];
      *reinterpret_cast<uint4*>(&a_lo[srow][16 * sc]) = sl[0];
      *reinterpret_cast<uint4*>(&a_lo[srow][16 * sc + 8]) = sl[1];
      size_t wb = (size_t)(co + srow) * Cc + k0 + 16 * sc;
      const uint4* th = reinterpret_cast<const uint4*>(&wfhi[wb]);
      const uint4* tl = reinterpret_cast<const uint4*>(&wflo[wb]);
      *reinterpret_cast<uint4*>(&b_hi[srow][16 * sc]) = th[0];
      *reinterpret_cast<uint4*>(&b_hi[srow][16 * sc + 8]) = th[1];
      *reinterpret_cast<uint4*>(&b_lo[srow][16 * sc]) = tl[0];
      *reinterpret_cast<uint4*>(&b_lo[srow][16 * sc + 8]) = tl[1];
    }
    __syncthreads();
    #pragma unroll
    for (int ks = 0; ks < 2; ks++) {
      s16x8 wb_hi = *reinterpret_cast<const s16x8*>(&b_hi[16 * w + l15][8 * g + 32 * ks]);
      s16x8 wb_lo = *reinterpret_cast<const s16x8*>(&b_lo[16 * w + l15][8 * g + 32 * ks]);
      #pragma unroll
      for (int mt = 0; mt < 4; mt++) {
        s16x8 aa_hi = *reinterpret_cast<const s16x8*>(&a_hi[16 * mt + l15][8 * g + 32 * ks]);
        s16x8 aa_lo = *reinterpret_cast<const s16x8*>(&a_lo[16 * mt + l15][8 * g + 32 * ks]);
        acc[mt] = MFMA16(aa_hi, wb_hi, acc[mt], 0, 0, 0);
        acc[mt] = MFMA16(aa_hi, wb_lo, acc[mt], 0, 0, 0);
        acc[mt] = MFMA16(aa_lo, wb_hi, acc[mt], 0, 0, 0);
      }
    }
  }
  int o = co + 16 * w + l15;
  float bfo = bf[o];
  #pragma unroll
  for (int mt = 0; mt < 4; mt++) {
    #pragma unroll
    for (int r = 0; r < 4; r++) {
      int row = ro + 16 * mt + 4 * g + r;
      out[(size_t)row * Cc + o] = x[(size_t)row * Cc + o] + acc[mt][r] + bfo;
    }
  }
}

// ---------------------------------------------------------------------------
extern "C" void kernel_launch(void* const* d_in, const int* in_sizes, int n_in,
                              void* d_out, int out_size, void* d_ws, size_t ws_size,
                              hipStream_t stream) {
  (void)in_sizes; (void)n_in; (void)out_size; (void)ws_size;
  const float* x     = (const float*)d_in[0];
  const float* gam   = (const float*)d_in[1];
  const float* bet   = (const float*)d_in[2];
  const float* Wqkv  = (const float*)d_in[3];
  const float* Wgate = (const float*)d_in[4];
  const float* bgate = (const float*)d_in[5];
  const float* Wf    = (const float*)d_in[6];
  const float* bf    = (const float*)d_in[7];
  float* out = (float*)d_out;
  float* ws  = (float*)d_ws;

  float* normed = ws + OFF_NORMED;
  float* gatep  = ws + OFF_GATE;
  float* mm     = ws + OFF_MM;
  float* mpart  = ws + OFF_MPART;
  float* lpart  = ws + OFF_LPART;
  u16*   qhi    = (u16*)(ws + OFF_QHI);
  u16*   whi    = (u16*)(ws + OFF_WHI);
  u16*   wlo    = (u16*)(ws + OFF_WLO);
  u16*   vtghi  = (u16*)(ws + OFF_VTGHI);
  u16*   aohi   = (u16*)(ws + OFF_AOHI);
  u16*   aolo   = (u16*)(ws + OFF_AOLO);
  u16*   p0     = (u16*)(ws + OFF_P0);
  u16*   p1     = (u16*)(ws + OFF_P1x);
  u16*   p2     = (u16*)(ws + OFF_P2);
  u16*   p3     = (u16*)(ws + OFF_P3);

  ln_kernel<<<NROWS, 256, 0, stream>>>(x, gam, bet, normed);
  wconv_kernel<<<1280, 256, 0, stream>>>(Wqkv, Wgate, Wf, whi, wlo);
  proj_kernel<<<dim3(16, 64), 256, 0, stream>>>(x, normed, whi, wlo, bgate,
                                                qhi, gatep);
  stats_kernel<<<dim3(32, 16, 4), 256, 0, stream>>>(qhi, mpart, lpart);
  merge_kernel<<<128, 256, 0, stream>>>(mpart, lpart, mm);
  vtrans_kernel<<<dim3(16, 16), 256, 0, stream>>>(qhi, vtghi);
  attnout_kernel<<<dim3(32, 16, 4), 256, 0, stream>>>(qhi, vtghi, mm,
                                                      p0, p1, p2, p3);
  combine_kernel<<<4096, 256, 0, stream>>>(p0, p1, p2, p3, gatep, aohi, aolo);
  final_kernel<<<dim3(4, 64), 256, 0, stream>>>(aohi, aolo,
                                                whi + 1024 * Cc, wlo + 1024 * Cc,
                                                bf, x, out);
}